// Round 4
// baseline (297.812 us; speedup 1.0000x reference)
//
#include <hip/hip_runtime.h>
#include <math.h>

#define T 2048
#define D 512
#define NH 8
#define DH 64
#define NB 4
#define NTOK (NB * T)   // 8192
#define LOG2E 1.44269504f
#define QSCALE (0.125f * LOG2E)

using bf16x8 = __attribute__((ext_vector_type(8))) short;
using f32x4  = __attribute__((ext_vector_type(4))) float;

static __device__ __forceinline__ unsigned short f2bf(float f) {
    union { float f; unsigned u; } v; v.f = f;
    unsigned r = v.u + 0x7fffu + ((v.u >> 16) & 1u);   // RNE
    return (unsigned short)(r >> 16);
}
// pack two floats -> two bf16 (RNE) in one word: low half = a, high = b
static __device__ __forceinline__ unsigned pack_bf16_pair(float a, float b) {
    union { float f; unsigned u; } ua, ub; ua.f = a; ub.f = b;
    unsigned ra = ua.u + 0x7fffu + ((ua.u >> 16) & 1u);
    unsigned rb = ub.u + 0x7fffu + ((ub.u >> 16) & 1u);
    return __builtin_amdgcn_perm(rb, ra, 0x07060302);
}

// ---------------- Kernel A: LayerNorm + mask + scaled label bias ------------
__global__ __launch_bounds__(256) void ln_kernel(
    const float* __restrict__ embs, const float* __restrict__ labels,
    const float* __restrict__ g, const float* __restrict__ bb,
    const float* __restrict__ alpha_p, const float* __restrict__ beta_p,
    unsigned short* __restrict__ xb, float* __restrict__ wscaled,
    float* __restrict__ kpmf)
{
    __shared__ float sm[8];
    int n = blockIdx.x;
    int tid = threadIdx.x;
    int lane = tid & 63, wid = tid >> 6;
    const float* e = embs + (size_t)n * D;
    float v0 = e[tid], v1 = e[tid + 256];

    float s = v0 + v1;
    #pragma unroll
    for (int o = 32; o; o >>= 1) s += __shfl_xor(s, o, 64);
    if (lane == 0) sm[wid] = s;
    __syncthreads();
    float mu = (sm[0] + sm[1] + sm[2] + sm[3]) * (1.0f / D);
    __syncthreads();

    float d0 = v0 - mu, d1 = v1 - mu;
    float ss = d0 * d0 + d1 * d1;
    #pragma unroll
    for (int o = 32; o; o >>= 1) ss += __shfl_xor(ss, o, 64);
    if (lane == 0) sm[wid] = ss;
    __syncthreads();
    float var = (sm[0] + sm[1] + sm[2] + sm[3]) * (1.0f / D);
    float rstd = rsqrtf(var + 1e-5f);

    float x0 = d0 * rstd * g[tid] + bb[tid];
    float x1 = d1 * rstd * g[tid + 256] + bb[tid + 256];
    xb[(size_t)n * D + tid] = f2bf(x0);
    xb[(size_t)n * D + tid + 256] = f2bf(x1);

    __syncthreads();
    float as = fabsf(x0) + fabsf(x1);
    #pragma unroll
    for (int o = 32; o; o >>= 1) as += __shfl_xor(as, o, 64);
    if (lane == 0) sm[wid] = as;
    __syncthreads();
    if (tid == 0) {
        float abssum = sm[0] + sm[1] + sm[2] + sm[3];
        int kpm = (abssum <= 1e-6f);
        kpmf[n] = kpm ? 1.0f : 0.0f;
        // exp2-scaled additive bias; masked -> huge negative (exp2 -> 0)
        wscaled[n] = kpm ? -3.0e38f
                         : (alpha_p[0] * labels[n] + beta_p[0]) * LOG2E;
    }
}

// ---------------- W -> bf16 conversion --------------------------------------
__global__ __launch_bounds__(256) void wconv_kernel(
    const float* __restrict__ w, unsigned short* __restrict__ wb)
{
    int i = (blockIdx.x * 256 + threadIdx.x) * 4;
    float4 f = *(const float4*)(w + i);
    ushort4 u;
    u.x = f2bf(f.x); u.y = f2bf(f.y); u.z = f2bf(f.z); u.w = f2bf(f.w);
    *(ushort4*)(wb + i) = u;
}

// ---------------- Kernel B: QKV projection, LDS-free MFMA -------------------
// 128x128 block tile, 4 waves in 2x2, each wave 64x64 (4x4 16x16 frags).
// q: [bh][t][dh] bf16 (pre-scaled by 0.125*log2e), k: [bh][t][dh] bf16,
// vt: [bh][dh][t] bf16
__global__ __launch_bounds__(256) void qkv_mfma(
    const unsigned short* __restrict__ xb, const unsigned short* __restrict__ wb,
    const float* __restrict__ bias, unsigned short* __restrict__ q,
    unsigned short* __restrict__ k, unsigned short* __restrict__ vt)
{
    int tid = threadIdx.x;
    int wave = tid >> 6, lane = tid & 63, quad = lane >> 4, lm = lane & 15;
    int wr = wave >> 1, wc = wave & 1;
    int m0 = blockIdx.x * 128 + wr * 64;   // token base for this wave
    int j0 = blockIdx.y * 128 + wc * 64;   // col base for this wave

    f32x4 acc[4][4];
    #pragma unroll
    for (int a = 0; a < 4; ++a)
        #pragma unroll
        for (int b = 0; b < 4; ++b) acc[a][b] = (f32x4){0.f,0.f,0.f,0.f};

    for (int kk = 0; kk < D; kk += 32) {
        bf16x8 af[4], bf[4];
        #pragma unroll
        for (int mf = 0; mf < 4; ++mf)
            af[mf] = *(const bf16x8*)(xb + (size_t)(m0 + mf * 16 + lm) * D + kk + quad * 8);
        #pragma unroll
        for (int nt = 0; nt < 4; ++nt)
            bf[nt] = *(const bf16x8*)(wb + (size_t)(j0 + nt * 16 + lm) * D + kk + quad * 8);
        #pragma unroll
        for (int mf = 0; mf < 4; ++mf)
            #pragma unroll
            for (int nt = 0; nt < 4; ++nt)
                acc[mf][nt] = __builtin_amdgcn_mfma_f32_16x16x32_bf16(af[mf], bf[nt], acc[mf][nt], 0, 0, 0);
    }

    #pragma unroll
    for (int nt = 0; nt < 4; ++nt) {
        int col = j0 + nt * 16 + lm;
        float bcol = bias[col];
        int part = col >> 9;           // 0=q,1=k,2=v
        int h = (col & 511) >> 6, dh = col & 63;
        #pragma unroll
        for (int mf = 0; mf < 4; ++mf) {
            #pragma unroll
            for (int r = 0; r < 4; ++r) {
                int tok = m0 + mf * 16 + quad * 4 + r;
                int b_ = tok >> 11, t = tok & (T - 1);
                int bh = b_ * NH + h;
                float val = acc[mf][nt][r] + bcol;
                if (part == 0)      q[((size_t)bh * T + t) * DH + dh] = f2bf(val * QSCALE);
                else if (part == 1) k[((size_t)bh * T + t) * DH + dh] = f2bf(val);
                else                vt[((size_t)bh * DH + dh) * T + t] = f2bf(val);
            }
        }
    }
}

// ---------------- Kernel C: flash attention, barrier-free, fused pooling ----
// Block = 128 queries of one bh; wave owns 32 queries. K/V fragments loaded
// directly from global (lane-addressable). Max-free softmax in exp2 domain.
// Key permutation within 64-tile: col (lm,nt) <-> key lm*4+nt, so P packs to
// b64 LDS writes and reads back naturally ordered.
__global__ __launch_bounds__(256) void attn_mfma(
    const unsigned short* __restrict__ q, const unsigned short* __restrict__ k,
    const unsigned short* __restrict__ vt, const float* __restrict__ wscaled,
    const float* __restrict__ kpmf, float* __restrict__ S)
{
    __shared__ __align__(16) unsigned short Ps[128][72];

    int tid = threadIdx.x, wave = tid >> 6, lane = tid & 63;
    int quad = lane >> 4, lm = lane & 15;
    int bh = blockIdx.x >> 4;
    int q0 = (blockIdx.x & 15) * 128;
    int b_ = bh >> 3, h = bh & 7;

    const unsigned short* qb = q + (size_t)bh * T * DH;
    const unsigned short* kb = k + (size_t)bh * T * DH;
    const unsigned short* vb = vt + (size_t)bh * DH * T;
    const float* wsb = wscaled + b_ * T;

    // persistent Q fragments (2 row-frags x 2 k-halves)
    bf16x8 qf[2][2];
    #pragma unroll
    for (int mf = 0; mf < 2; ++mf)
        #pragma unroll
        for (int kk = 0; kk < 2; ++kk)
            qf[mf][kk] = *(const bf16x8*)(qb + (size_t)(q0 + wave * 32 + mf * 16 + lm) * DH + kk * 32 + quad * 8);

    f32x4 accO[2][4];
    float l_part[2][4];
    #pragma unroll
    for (int mf = 0; mf < 2; ++mf)
        #pragma unroll
        for (int nt = 0; nt < 4; ++nt) accO[mf][nt] = (f32x4){0.f,0.f,0.f,0.f};
    #pragma unroll
    for (int mf = 0; mf < 2; ++mf)
        #pragma unroll
        for (int r = 0; r < 4; ++r) l_part[mf][r] = 0.f;

    for (int j0t = 0; j0t < T; j0t += 64) {
        // K fragments, permuted: column (lm, frag nt) holds key j0t + lm*4 + nt
        bf16x8 kf[4][2];
        float bias[4];
        #pragma unroll
        for (int nt = 0; nt < 4; ++nt) {
            int key = j0t + lm * 4 + nt;
            #pragma unroll
            for (int kk = 0; kk < 2; ++kk)
                kf[nt][kk] = *(const bf16x8*)(kb + (size_t)key * DH + kk * 32 + quad * 8);
            bias[nt] = wsb[key];
        }

        // S = Q.K^T (exp2 domain; q pre-scaled)
        f32x4 s[2][4];
        #pragma unroll
        for (int mf = 0; mf < 2; ++mf)
            #pragma unroll
            for (int nt = 0; nt < 4; ++nt) {
                f32x4 t0 = (f32x4){0.f,0.f,0.f,0.f};
                t0 = __builtin_amdgcn_mfma_f32_16x16x32_bf16(qf[mf][0], kf[nt][0], t0, 0, 0, 0);
                t0 = __builtin_amdgcn_mfma_f32_16x16x32_bf16(qf[mf][1], kf[nt][1], t0, 0, 0, 0);
                s[mf][nt] = t0;
            }

        // p = exp2(s + bias); pack 4 keys (nt) -> one b64 LDS write
        #pragma unroll
        for (int mf = 0; mf < 2; ++mf) {
            int rowb = wave * 32 + mf * 16 + quad * 4;
            #pragma unroll
            for (int r = 0; r < 4; ++r) {
                float p0 = __builtin_amdgcn_exp2f(s[mf][0][r] + bias[0]);
                float p1 = __builtin_amdgcn_exp2f(s[mf][1][r] + bias[1]);
                float p2 = __builtin_amdgcn_exp2f(s[mf][2][r] + bias[2]);
                float p3 = __builtin_amdgcn_exp2f(s[mf][3][r] + bias[3]);
                l_part[mf][r] += (p0 + p1) + (p2 + p3);
                uint2 pw;
                pw.x = pack_bf16_pair(p0, p1);
                pw.y = pack_bf16_pair(p2, p3);
                *(uint2*)&Ps[rowb + r][lm * 4] = pw;   // Ps[row][c] = key j0t+c
            }
        }

        // V fragments (natural order) + P fragments (own rows; in-wave dep)
        bf16x8 vf[4][2], pf[2][2];
        #pragma unroll
        for (int nt = 0; nt < 4; ++nt)
            #pragma unroll
            for (int kk = 0; kk < 2; ++kk)
                vf[nt][kk] = *(const bf16x8*)(vb + (size_t)(nt * 16 + lm) * T + j0t + kk * 32 + quad * 8);
        #pragma unroll
        for (int mf = 0; mf < 2; ++mf)
            #pragma unroll
            for (int kk = 0; kk < 2; ++kk)
                pf[mf][kk] = *(const bf16x8*)&Ps[wave * 32 + mf * 16 + lm][kk * 32 + quad * 8];

        #pragma unroll
        for (int mf = 0; mf < 2; ++mf)
            #pragma unroll
            for (int nt = 0; nt < 4; ++nt) {
                accO[mf][nt] = __builtin_amdgcn_mfma_f32_16x16x32_bf16(pf[mf][0], vf[nt][0], accO[mf][nt], 0, 0, 0);
                accO[mf][nt] = __builtin_amdgcn_mfma_f32_16x16x32_bf16(pf[mf][1], vf[nt][1], accO[mf][nt], 0, 0, 0);
            }
    }

    // finish l: sum across the 16 col-owning lanes (lane bits 0..3)
    #pragma unroll
    for (int mf = 0; mf < 2; ++mf)
        #pragma unroll
        for (int r = 0; r < 4; ++r) {
            float lv = l_part[mf][r];
            #pragma unroll
            for (int off = 1; off <= 8; off <<= 1) lv += __shfl_xor(lv, off, 64);
            l_part[mf][r] = lv;
        }

    // fused masked pooling: pooled[dh] += sum_rows accO/l * (1-kp)
    float pooled[4] = {0.f, 0.f, 0.f, 0.f};
    #pragma unroll
    for (int mf = 0; mf < 2; ++mf)
        #pragma unroll
        for (int r = 0; r < 4; ++r) {
            int row = q0 + wave * 32 + mf * 16 + quad * 4 + r;
            float w = (1.0f - kpmf[b_ * T + row]) / l_part[mf][r];
            #pragma unroll
            for (int nt = 0; nt < 4; ++nt) pooled[nt] += accO[mf][nt][r] * w;
        }
    #pragma unroll
    for (int nt = 0; nt < 4; ++nt) {
        pooled[nt] += __shfl_xor(pooled[nt], 16, 64);
        pooled[nt] += __shfl_xor(pooled[nt], 32, 64);
    }
    if (quad == 0) {
        #pragma unroll
        for (int nt = 0; nt < 4; ++nt)
            atomicAdd(&S[b_ * D + h * DH + nt * 16 + lm], pooled[nt]);
    }
}

// ---------------- Kernel E: out-projection of pooled vector + bias ----------
__global__ __launch_bounds__(256) void out_kernel(
    const float* __restrict__ S, const float* __restrict__ kpmf,
    const float* __restrict__ Wo, const float* __restrict__ bo,
    float* __restrict__ out)
{
    __shared__ float Sl[512];
    __shared__ float cs[4];
    int b_ = blockIdx.x;
    int tid = threadIdx.x;
    Sl[tid] = S[b_ * D + tid];
    Sl[tid + 256] = S[b_ * D + tid + 256];
    const float* kp = kpmf + b_ * T;
    float c = 0.f;
    for (int t = tid; t < T; t += 256) c += kp[t];
    #pragma unroll
    for (int o = 32; o; o >>= 1) c += __shfl_xor(c, o, 64);
    if ((tid & 63) == 0) cs[tid >> 6] = c;
    __syncthreads();
    float masked = cs[0] + cs[1] + cs[2] + cs[3];
    float cnt = (float)T - masked;
    float inv = 1.0f / fmaxf(cnt, 1.0f);
    #pragma unroll
    for (int p = 0; p < 2; ++p) {
        int d = tid + p * 256;
        const float4* wr4 = (const float4*)(Wo + (size_t)d * D);
        float dot = 0.f;
        for (int k4 = 0; k4 < D / 4; ++k4) {
            float4 w4 = wr4[k4];
            dot += Sl[4 * k4 + 0] * w4.x + Sl[4 * k4 + 1] * w4.y +
                   Sl[4 * k4 + 2] * w4.z + Sl[4 * k4 + 3] * w4.w;
        }
        out[b_ * D + d] = (dot + bo[d] * cnt) * inv;
    }
}

extern "C" void kernel_launch(void* const* d_in, const int* in_sizes, int n_in,
                              void* d_out, int out_size, void* d_ws, size_t ws_size,
                              hipStream_t stream) {
    const float* embs   = (const float*)d_in[0];
    const float* labels = (const float*)d_in[1];
    const float* ln_g   = (const float*)d_in[2];
    const float* ln_b   = (const float*)d_in[3];
    const float* ipw    = (const float*)d_in[4];
    const float* ipb    = (const float*)d_in[5];
    const float* ow     = (const float*)d_in[6];
    const float* obb    = (const float*)d_in[7];
    const float* alpha  = (const float*)d_in[8];
    const float* beta   = (const float*)d_in[9];
    float* out = (float*)d_out;

    unsigned short* xb = (unsigned short*)d_ws;          // 8192*512 bf16
    unsigned short* wb = xb + (size_t)NTOK * D;          // 1536*512 bf16
    unsigned short* q  = wb + (size_t)3 * D * D;         // 8192*512 bf16
    unsigned short* k  = q  + (size_t)NTOK * D;
    unsigned short* vt = k  + (size_t)NTOK * D;
    float* wscaled = (float*)(vt + (size_t)NTOK * D);    // 8192 f32
    float* kpmf    = wscaled + NTOK;                     // 8192
    float* S       = kpmf + NTOK;                        // 2048

    hipMemsetAsync(S, 0, (size_t)NB * D * sizeof(float), stream);
    ln_kernel<<<NTOK, 256, 0, stream>>>(embs, labels, ln_g, ln_b, alpha, beta,
                                        xb, wscaled, kpmf);
    wconv_kernel<<<(3 * D * D) / 1024, 256, 0, stream>>>(ipw, wb);
    dim3 gq(NTOK / 128, (3 * D) / 128);
    qkv_mfma<<<gq, 256, 0, stream>>>(xb, wb, ipb, q, k, vt);
    attn_mfma<<<NB * NH * (T / 128), 256, 0, stream>>>(q, k, vt, wscaled, kpmf, S);
    out_kernel<<<NB, 256, 0, stream>>>(S, kpmf, ow, obb, out);
}